// Round 8
// baseline (284.061 us; speedup 1.0000x reference)
//
#include <hip/hip_runtime.h>
#include <math.h>

#define DD 1024
#define NB 16
#define WSPLIT 32
#define HSPLIT 32

typedef unsigned short u16;
typedef __attribute__((ext_vector_type(8))) short short8;
typedef __attribute__((ext_vector_type(4))) float f32x4;
typedef __attribute__((ext_vector_type(16))) float f32x16;

__device__ __forceinline__ float gelu_f(float x) {
  return 0.5f * x * (1.0f + erff(x * 0.70710678118654752440f));
}
__device__ __forceinline__ u16 f2bf(float f) {
  union { float f; unsigned u; } v; v.f = f;
  return (u16)((v.u + 0x7FFFu + ((v.u >> 16) & 1u)) >> 16);
}
__device__ __forceinline__ float bf2f(u16 b) {
  union { unsigned u; float f; } v; v.u = ((unsigned)b) << 16;
  return v.f;
}
__device__ __forceinline__ void gload_lds16(const u16* g, u16* l) {
  __builtin_amdgcn_global_load_lds(
      (const __attribute__((address_space(1))) void*)g,
      (__attribute__((address_space(3))) void*)l, 16, 0, 0);
}

#define VMCNT8   asm volatile("s_waitcnt vmcnt(8)" ::: "memory")
#define VMCNT0   asm volatile("s_waitcnt vmcnt(0)" ::: "memory")
#define BARRIER  asm volatile("s_barrier" ::: "memory")

// ---- fused prep: cvt x | LN | transpose+cvt base_down | cvt base_up ----
__launch_bounds__(256)
__global__ void prep_kernel(const float* __restrict__ x, u16* __restrict__ xb,
                            const float* __restrict__ ada, const float* __restrict__ gamma,
                            const float* __restrict__ beta, float* __restrict__ c,
                            const float* __restrict__ bdn, u16* __restrict__ bdTb,
                            const float* __restrict__ bu, u16* __restrict__ bub) {
  __shared__ float smem[1056];
  int bid = blockIdx.x;
  int t = threadIdx.x;
  if (bid < 8192) {
    size_t i = (size_t)bid * 256 + t;
    const float4* xf = (const float4*)x;
    float4 v0 = xf[i * 2], v1 = xf[i * 2 + 1];
    short8 o;
    o[0] = (short)f2bf(v0.x); o[1] = (short)f2bf(v0.y);
    o[2] = (short)f2bf(v0.z); o[3] = (short)f2bf(v0.w);
    o[4] = (short)f2bf(v1.x); o[5] = (short)f2bf(v1.y);
    o[6] = (short)f2bf(v1.z); o[7] = (short)f2bf(v1.w);
    *(short8*)(xb + i * 8) = o;
  } else if (bid < 8208) {
    int b = bid - 8192;
    const float* row = ada + b * DD;
    float s = 0.f, s2 = 0.f;
    for (int i = t; i < DD; i += 256) { float v = row[i]; s += v; s2 += v * v; }
    for (int off = 32; off; off >>= 1) { s += __shfl_down(s, off); s2 += __shfl_down(s2, off); }
    float* rs = smem; float* rs2 = smem + 4;
    int wave = t >> 6, lane = t & 63;
    if (lane == 0) { rs[wave] = s; rs2[wave] = s2; }
    __syncthreads();
    if (t == 0) {
      float a = 0.f, a2 = 0.f;
      for (int w = 0; w < 4; w++) { a += rs[w]; a2 += rs2[w]; }
      rs[0] = a * (1.0f / DD); rs2[0] = a2 * (1.0f / DD);
    }
    __syncthreads();
    float mu = rs[0];
    float var = rs2[0] - mu * mu;
    float inv = rsqrtf(var + 1e-5f);
    for (int i = t; i < DD; i += 256)
      c[b * DD + i] = (row[i] - mu) * inv * gamma[i] + beta[i];
  } else if (bid < 9232) {
    int t2 = bid - 8208;
    int bx = (t2 & 31) * 32, by = (t2 >> 5) * 32;
    float (*tile)[33] = (float(*)[33])smem;
    int tx = t & 31, ty = t >> 5;   // 32 x 8
    for (int r = ty; r < 32; r += 8) tile[r][tx] = bdn[(size_t)(by + r) * DD + bx + tx];
    __syncthreads();
    for (int r = ty; r < 32; r += 8)
      bdTb[(size_t)(bx + r) * DD + by + tx] = f2bf(tile[tx][r]);
  } else {
    size_t i = (size_t)(bid - 9232) * 256 + t;
    const float4* bf = (const float4*)bu;
    float4 v0 = bf[i * 2], v1 = bf[i * 2 + 1];
    short8 o;
    o[0] = (short)f2bf(v0.x); o[1] = (short)f2bf(v0.y);
    o[2] = (short)f2bf(v0.z); o[3] = (short)f2bf(v0.w);
    o[4] = (short)f2bf(v1.x); o[5] = (short)f2bf(v1.y);
    o[6] = (short)f2bf(v1.z); o[7] = (short)f2bf(v1.w);
    *(short8*)(bub + i * 8) = o;
  }
}

// ------- h partials: split-K over W1 (32 splits of 32) -------
__launch_bounds__(256)
__global__ void h_part_kernel(const float* __restrict__ c, const float* __restrict__ W1,
                              float* __restrict__ hpart) {
  int s = blockIdx.y;
  int j = blockIdx.x * 256 + threadIdx.x;
  int k0 = s * 32;
  __shared__ float cs[NB][32];
  for (int i = threadIdx.x; i < NB * 32; i += 256)
    cs[i >> 5][i & 31] = c[(size_t)(i >> 5) * DD + k0 + (i & 31)];
  __syncthreads();
  float acc[NB];
  #pragma unroll
  for (int b = 0; b < NB; b++) acc[b] = 0.f;
  #pragma unroll
  for (int al = 0; al < 32; al++) {
    float wv = W1[(size_t)(k0 + al) * DD + j];
    #pragma unroll
    for (int b = 0; b < NB; b++) acc[b] += cs[b][al] * wv;
  }
  #pragma unroll
  for (int b = 0; b < NB; b++)
    hpart[((size_t)s * NB + b) * DD + j] = acc[b];
}

// ------- w partials: split-K over W2 (32 splits of 32), h-reduce fused -------
__launch_bounds__(256)
__global__ void w_part_kernel(const float* __restrict__ hpart, const float* __restrict__ bias1,
                              const float* __restrict__ W2, float* __restrict__ part) {
  int s = blockIdx.y;                          // k-split, 0..31
  int j4 = blockIdx.x * 256 + threadIdx.x;     // float4 column, 0..8191
  int k0 = s * 32;
  int t = threadIdx.x;
  __shared__ float hl[NB][32];                 // 2 KB
  // fused h_reduce: h[b][k0+kk] = gelu(bias1 + sum_s hpart)
  #pragma unroll
  for (int v = 0; v < 2; v++) {
    int i = t + v * 256;                       // 0..511 -> (b, kk)
    int b = i >> 5, kk = i & 31;
    float acc = bias1[k0 + kk];
    #pragma unroll 8
    for (int ss = 0; ss < HSPLIT; ss++) acc += hpart[((size_t)ss * NB + b) * DD + k0 + kk];
    hl[b][kk] = gelu_f(acc);
  }
  __syncthreads();
  f32x4 acc[NB];
  #pragma unroll
  for (int b = 0; b < NB; b++) acc[b] = f32x4{0.f, 0.f, 0.f, 0.f};
  const float4* W2v = (const float4*)W2;
  #pragma unroll 8
  for (int al = 0; al < 32; al++) {
    float4 wv = W2v[(size_t)(k0 + al) * 8192 + j4];
    #pragma unroll
    for (int b = 0; b < NB; b++) {
      float hb = hl[b][al];
      acc[b][0] += hb * wv.x; acc[b][1] += hb * wv.y;
      acc[b][2] += hb * wv.z; acc[b][3] += hb * wv.w;
    }
  }
  f32x4* pv = (f32x4*)part;
  #pragma unroll
  for (int b = 0; b < NB; b++)
    pv[((size_t)s * NB + b) * 8192 + j4] = acc[b];
}

// ------- w = sum_s part[s] + bias2 -------
__launch_bounds__(256)
__global__ void w_reduce_kernel(const float* __restrict__ part, const float* __restrict__ bias2,
                                float* __restrict__ w) {
  int idx = blockIdx.x * 256 + threadIdx.x;
  int j = idx & 32767;
  float acc = bias2[j];
  #pragma unroll
  for (int s = 0; s < WSPLIT; s++) acc += part[(size_t)s * NB * 32768 + idx];
  w[idx] = acc;
}

// ---- pack_lora: aext = zero-pad8(src @ colfactor), bext = zero-pad8(rowfactor) ----
__launch_bounds__(256)
__global__ void pack_lora_kernel(const u16* __restrict__ src, const float* __restrict__ w,
                                 int aoff, int boff,
                                 u16* __restrict__ aext, u16* __restrict__ bext) {
  int b = blockIdx.y;
  const float* wb = w + (size_t)b * 32768;
  int t = threadIdx.x;
  short8 z = {};
  if (blockIdx.x < 16) {
    __shared__ float a2s[8192];   // 32 KB col factor [d][r]
    for (int i = t; i < 8192; i += 256) a2s[i] = wb[aoff + i];
    __syncthreads();
    int row = blockIdx.x * 64 + (t >> 2);
    int q = t & 3;
    const u16* xr = src + ((size_t)b << 20) + (size_t)row * DD + q * 256;
    float acc[8] = {};
    #pragma unroll 4
    for (int kk = 0; kk < 32; kk++) {
      short8 xv = *(const short8*)(xr + kk * 8);
      #pragma unroll
      for (int e = 0; e < 8; e++) {
        float xf = bf2f((u16)xv[e]);
        int d = q * 256 + kk * 8 + e;
        #pragma unroll
        for (int r = 0; r < 8; r++) acc[r] += xf * a2s[d * 8 + r];
      }
    }
    #pragma unroll
    for (int r = 0; r < 8; r++) {
      acc[r] += __shfl_xor(acc[r], 1);
      acc[r] += __shfl_xor(acc[r], 2);
    }
    short8 ov = z;
    if (q == 0) {
      #pragma unroll
      for (int r = 0; r < 8; r++) ov[r] = (short)f2bf(acc[r]);
    }
    u16* orow = aext + ((size_t)b * 1024 + row) * 64 + q * 16;
    *(short8*)orow = ov;
    *(short8*)(orow + 8) = z;
  } else {
    for (int l = t; l < 1024; l += 256) {
      short8 ov;
      #pragma unroll
      for (int r = 0; r < 8; r++) ov[r] = (short)f2bf(wb[boff + l * 8 + r]);
      u16* orow = bext + ((size_t)b * 1024 + l) * 64;
      *(short8*)orow = ov;
      #pragma unroll
      for (int k = 1; k < 8; k++) *(short8*)(orow + k * 8) = z;
    }
  }
}

// ------- batched GEMM 256x256 tile, 8 waves, 4-phase, 32x32x16 MFMA, K=1024+64 -------
#define STAGE_A(KT, BUF) do { int kt_ = (KT);                                          \
    if (kt_ < 16) { int ks_ = kt_ * 64;                                                \
      _Pragma("unroll")                                                                \
      for (int c_ = 0; c_ < 4; c_++)                                                   \
        gload_lds16(Ab + (size_t)srow[c_] * DD + ks_ + se[c_], As[BUF] + ldsel[c_]);   \
    } else {                                                                           \
      _Pragma("unroll")                                                                \
      for (int c_ = 0; c_ < 4; c_++)                                                   \
        gload_lds16(Ae + (size_t)srow[c_] * 64 + se[c_], As[BUF] + ldsel[c_]);         \
    } } while (0)
#define STAGE_B(KT, BUF) do { int kt_ = (KT);                                          \
    if (kt_ < 16) { int ks_ = kt_ * 64;                                                \
      _Pragma("unroll")                                                                \
      for (int c_ = 0; c_ < 4; c_++)                                                   \
        gload_lds16(Bb + (size_t)srow[c_] * DD + ks_ + se[c_], Bs[BUF] + ldsel[c_]);   \
    } else {                                                                           \
      _Pragma("unroll")                                                                \
      for (int c_ = 0; c_ < 4; c_++)                                                   \
        gload_lds16(Be + (size_t)srow[c_] * 64 + se[c_], Bs[BUF] + ldsel[c_]);         \
    } } while (0)

template<int PHASE>
__launch_bounds__(512, 2)
__global__ void gemm256_kernel(const u16* __restrict__ A, const u16* __restrict__ BT,
                               const u16* __restrict__ Aext, const u16* __restrict__ Bext,
                               const u16* __restrict__ resid, void* __restrict__ Cout) {
  constexpr int BK = 64;
  constexpr int NT = 17;
  __shared__ __align__(16) u16 As[2][256 * BK];
  __shared__ __align__(16) u16 Bs[2][256 * BK];

  int orig = blockIdx.x;
  int logical = (orig & 7) * 32 + (orig >> 3);
  int b = logical >> 4;
  int tile = logical & 15;
  int tm = tile >> 2, tn = tile & 3;

  const u16* Ab = A + ((size_t)b << 20) + (size_t)(tm * 256) * DD;
  const u16* Bb = BT + (size_t)(tn * 256) * DD;                       // batch-shared
  const u16* Ae = Aext + ((size_t)b * 1024 + tm * 256) * 64;
  const u16* Be = Bext + ((size_t)b * 1024 + tn * 256) * 64;

  int t = threadIdx.x, lane = t & 63;
  int l31 = lane & 31, kb = (lane >> 5) * 8;   // k-octet select for 32x32 frags
  int wave = t >> 6;
  int wm = wave >> 2, wn = wave & 3;           // per-wave 128 x 64 output

  int srow[4], se[4], ldsel[4];
  #pragma unroll
  for (int c = 0; c < 4; c++) {
    int chunk = c * 512 + t;
    srow[c] = chunk >> 3;
    se[c] = ((chunk & 7) ^ (srow[c] & 7)) << 3;
    ldsel[c] = chunk * 8;
  }

  f32x16 acc[4][2] = {};    // 4 row-tiles(32) x 2 col-tiles(32)

  STAGE_A(0, 0); STAGE_B(0, 0);
  STAGE_A(1, 1); STAGE_B(1, 1);
  VMCNT8;
  BARRIER;

  int cur = 0;
  #pragma unroll 1
  for (int kt = 0; kt < NT; kt++) {
    const u16* Ap = As[cur];
    const u16* Bp = Bs[cur];
    short8 afr[2][4], bf0[4], bf1[4];   // [rt][ks] / [ks]

    // ---- ph0: read A rt{0,1} (8) + B ct0 (4); Q00 ----
    #pragma unroll
    for (int ks = 0; ks < 4; ks++) {
      #pragma unroll
      for (int rt = 0; rt < 2; rt++) {
        int r = wm * 128 + rt * 32 + l31;
        int e = (ks * 16 + kb) ^ ((r & 7) << 3);
        afr[rt][ks] = *(const short8*)(Ap + r * BK + e);
      }
      {
        int r = wn * 64 + l31;
        int e = (ks * 16 + kb) ^ ((r & 7) << 3);
        bf0[ks] = *(const short8*)(Bp + r * BK + e);
      }
    }
    BARRIER;
    __builtin_amdgcn_s_setprio(1);
    #pragma unroll
    for (int ks = 0; ks < 4; ks++)
      #pragma unroll
      for (int rt = 0; rt < 2; rt++)
        acc[rt][0] = __builtin_amdgcn_mfma_f32_32x32x16_bf16(afr[rt][ks], bf0[ks], acc[rt][0], 0, 0, 0);
    __builtin_amdgcn_s_setprio(0);
    BARRIER;

    // ---- ph1: read B ct1 (4); Q01 ----
    #pragma unroll
    for (int ks = 0; ks < 4; ks++) {
      int r = wn * 64 + 32 + l31;
      int e = (ks * 16 + kb) ^ ((r & 7) << 3);
      bf1[ks] = *(const short8*)(Bp + r * BK + e);
    }
    BARRIER;
    __builtin_amdgcn_s_setprio(1);
    #pragma unroll
    for (int ks = 0; ks < 4; ks++)
      #pragma unroll
      for (int rt = 0; rt < 2; rt++)
        acc[rt][1] = __builtin_amdgcn_mfma_f32_32x32x16_bf16(afr[rt][ks], bf1[ks], acc[rt][1], 0, 0, 0);
    __builtin_amdgcn_s_setprio(0);
    BARRIER;
    // all B reads of buf[cur] done -> B slot free

    // ---- ph2: stage B(kt+2); read A rt{2,3} (8); Q11 ----
    if (kt + 2 < NT) STAGE_B(kt + 2, cur);
    #pragma unroll
    for (int ks = 0; ks < 4; ks++)
      #pragma unroll
      for (int rt = 0; rt < 2; rt++) {
        int r = wm * 128 + (rt + 2) * 32 + l31;
        int e = (ks * 16 + kb) ^ ((r & 7) << 3);
        afr[rt][ks] = *(const short8*)(Ap + r * BK + e);
      }
    BARRIER;
    __builtin_amdgcn_s_setprio(1);
    #pragma unroll
    for (int ks = 0; ks < 4; ks++)
      #pragma unroll
      for (int rt = 0; rt < 2; rt++)
        acc[rt + 2][1] = __builtin_amdgcn_mfma_f32_32x32x16_bf16(afr[rt][ks], bf1[ks], acc[rt + 2][1], 0, 0, 0);
    __builtin_amdgcn_s_setprio(0);
    BARRIER;
    // all A reads of buf[cur] done -> A slot free

    // ---- ph3: stage A(kt+2); Q10 (regs only); tile-boundary wait ----
    if (kt + 2 < NT) STAGE_A(kt + 2, cur);
    __builtin_amdgcn_s_setprio(1);
    #pragma unroll
    for (int ks = 0; ks < 4; ks++)
      #pragma unroll
      for (int rt = 0; rt < 2; rt++)
        acc[rt + 2][0] = __builtin_amdgcn_mfma_f32_32x32x16_bf16(afr[rt][ks], bf0[ks], acc[rt + 2][0], 0, 0, 0);
    __builtin_amdgcn_s_setprio(0);
    if (kt + 2 < NT) { VMCNT8; } else { VMCNT0; }
    BARRIER;

    cur ^= 1;
  }

  // C/D map (verified m74/m101): col = l31, row = (reg&3) + 8*(reg>>2) + 4*(lane>>5)
  int r0 = tm * 256 + wm * 128 + (lane >> 5) * 4;
  int c0 = tn * 256 + wn * 64 + l31;
  if (PHASE == 1) {
    u16* mid = (u16*)Cout + ((size_t)b << 20);
    #pragma unroll
    for (int rt = 0; rt < 4; rt++)
      #pragma unroll
      for (int ct = 0; ct < 2; ct++)
        #pragma unroll
        for (int reg = 0; reg < 16; reg++) {
          int row = r0 + rt * 32 + (reg & 3) + 8 * (reg >> 2);
          int col = c0 + ct * 32;
          mid[(size_t)row * DD + col] = f2bf(gelu_f(acc[rt][ct][reg]));
        }
  } else {
    float* out = (float*)Cout + ((size_t)b << 20);
    const u16* xb = resid + ((size_t)b << 20);
    #pragma unroll
    for (int rt = 0; rt < 4; rt++)
      #pragma unroll
      for (int ct = 0; ct < 2; ct++)
        #pragma unroll
        for (int reg = 0; reg < 16; reg++) {
          int row = r0 + rt * 32 + (reg & 3) + 8 * (reg >> 2);
          int col = c0 + ct * 32;
          size_t idx = (size_t)row * DD + col;
          out[idx] = bf2f(xb[idx]) + acc[rt][ct][reg];
        }
  }
}

extern "C" void kernel_launch(void* const* d_in, const int* in_sizes, int n_in,
                              void* d_out, int out_size, void* d_ws, size_t ws_size,
                              hipStream_t stream) {
  const float* x         = (const float*)d_in[0];
  const float* ada       = (const float*)d_in[1];
  const float* base_up   = (const float*)d_in[2];
  const float* base_down = (const float*)d_in[3];
  const float* gamma     = (const float*)d_in[4];
  const float* beta      = (const float*)d_in[5];
  const float* W1        = (const float*)d_in[6];
  const float* bias1     = (const float*)d_in[7];
  const float* W2        = (const float*)d_in[8];
  const float* bias2     = (const float*)d_in[9];
  float* out = (float*)d_out;
  char* ws = (char*)d_ws;

  float* c     = (float*)(ws);                 // 64 KB
  float* w     = (float*)(ws + 0x20000);       // 2 MB
  u16*   bdTb  = (u16*)  (ws + 0x220000);      // 2 MB
  u16*   bub   = (u16*)  (ws + 0x420000);      // 2 MB
  float* hpart = (float*)(ws + 0x620000);      // 2 MB
  u16*   xb    = (u16*)  (ws + 0x820000);      // 32 MB
  u16*   uext  = (u16*)  (ws + 0x2820000);     // 2 MB
  u16*   b2ext = (u16*)  (ws + 0x2A20000);     // 2 MB
  u16*   vext  = (u16*)  (ws + 0x2C20000);     // 2 MB
  u16*   a1ext = (u16*)  (ws + 0x2E20000);     // 2 MB
  u16*   mid   = (u16*)  (ws + 0x3020000);     // 32 MB
  float* part  = (float*)(ws + 0x5020000);     // 64 MB

  prep_kernel<<<dim3(9744), dim3(256), 0, stream>>>(x, xb, ada, gamma, beta, c,
                                                    base_down, bdTb, base_up, bub);
  h_part_kernel<<<dim3(4, HSPLIT), dim3(256), 0, stream>>>(c, W1, hpart);
  w_part_kernel<<<dim3(32, WSPLIT), dim3(256), 0, stream>>>(hpart, bias1, W2, part);
  w_reduce_kernel<<<dim3(2048), dim3(256), 0, stream>>>(part, bias2, w);
  pack_lora_kernel<<<dim3(17, 16), dim3(256), 0, stream>>>(xb, w, 16384, 24576, uext, b2ext);
  gemm256_kernel<1><<<dim3(256), dim3(512), 0, stream>>>(xb, bdTb, uext, b2ext,
                                                         (const u16*)nullptr, (void*)mid);
  pack_lora_kernel<<<dim3(17, 16), dim3(256), 0, stream>>>(mid, w, 8192, 0, vext, a1ext);
  gemm256_kernel<2><<<dim3(256), dim3(512), 0, stream>>>(mid, bub, vext, a1ext, xb, (void*)out);
}

// Round 9
// 258.113 us; speedup vs baseline: 1.1005x; 1.1005x over previous
//
#include <hip/hip_runtime.h>
#include <math.h>

#define DD 1024
#define NB 16
#define WSPLIT 16
#define HSPLIT 32

typedef unsigned short u16;
typedef __attribute__((ext_vector_type(8))) short short8;
typedef __attribute__((ext_vector_type(4))) float f32x4;
typedef __attribute__((ext_vector_type(16))) float f32x16;

__device__ __forceinline__ float gelu_f(float x) {
  return 0.5f * x * (1.0f + erff(x * 0.70710678118654752440f));
}
__device__ __forceinline__ u16 f2bf(float f) {
  union { float f; unsigned u; } v; v.f = f;
  return (u16)((v.u + 0x7FFFu + ((v.u >> 16) & 1u)) >> 16);
}
__device__ __forceinline__ float bf2f(u16 b) {
  union { unsigned u; float f; } v; v.u = ((unsigned)b) << 16;
  return v.f;
}
__device__ __forceinline__ void gload_lds16(const u16* g, u16* l) {
  __builtin_amdgcn_global_load_lds(
      (const __attribute__((address_space(1))) void*)g,
      (__attribute__((address_space(3))) void*)l, 16, 0, 0);
}
__device__ __forceinline__ void gload_lds16f(const float* g, float* l) {
  __builtin_amdgcn_global_load_lds(
      (const __attribute__((address_space(1))) void*)g,
      (__attribute__((address_space(3))) void*)l, 16, 0, 0);
}

#define VMCNT8   asm volatile("s_waitcnt vmcnt(8)" ::: "memory")
#define VMCNT0   asm volatile("s_waitcnt vmcnt(0)" ::: "memory")
#define BARRIER  asm volatile("s_barrier" ::: "memory")

// ---- fused prep: cvt x | LN | transpose+cvt base_down | cvt base_up ----
__launch_bounds__(256)
__global__ void prep_kernel(const float* __restrict__ x, u16* __restrict__ xb,
                            const float* __restrict__ ada, const float* __restrict__ gamma,
                            const float* __restrict__ beta, float* __restrict__ c,
                            const float* __restrict__ bdn, u16* __restrict__ bdTb,
                            const float* __restrict__ bu, u16* __restrict__ bub) {
  __shared__ float smem[1056];
  int bid = blockIdx.x;
  int t = threadIdx.x;
  if (bid < 8192) {
    size_t i = (size_t)bid * 256 + t;
    const float4* xf = (const float4*)x;
    float4 v0 = xf[i * 2], v1 = xf[i * 2 + 1];
    short8 o;
    o[0] = (short)f2bf(v0.x); o[1] = (short)f2bf(v0.y);
    o[2] = (short)f2bf(v0.z); o[3] = (short)f2bf(v0.w);
    o[4] = (short)f2bf(v1.x); o[5] = (short)f2bf(v1.y);
    o[6] = (short)f2bf(v1.z); o[7] = (short)f2bf(v1.w);
    *(short8*)(xb + i * 8) = o;
  } else if (bid < 8208) {
    int b = bid - 8192;
    const float* row = ada + b * DD;
    float s = 0.f, s2 = 0.f;
    for (int i = t; i < DD; i += 256) { float v = row[i]; s += v; s2 += v * v; }
    for (int off = 32; off; off >>= 1) { s += __shfl_down(s, off); s2 += __shfl_down(s2, off); }
    float* rs = smem; float* rs2 = smem + 4;
    int wave = t >> 6, lane = t & 63;
    if (lane == 0) { rs[wave] = s; rs2[wave] = s2; }
    __syncthreads();
    if (t == 0) {
      float a = 0.f, a2 = 0.f;
      for (int w = 0; w < 4; w++) { a += rs[w]; a2 += rs2[w]; }
      rs[0] = a * (1.0f / DD); rs2[0] = a2 * (1.0f / DD);
    }
    __syncthreads();
    float mu = rs[0];
    float var = rs2[0] - mu * mu;
    float inv = rsqrtf(var + 1e-5f);
    for (int i = t; i < DD; i += 256)
      c[b * DD + i] = (row[i] - mu) * inv * gamma[i] + beta[i];
  } else if (bid < 9232) {
    int t2 = bid - 8208;
    int bx = (t2 & 31) * 32, by = (t2 >> 5) * 32;
    float (*tile)[33] = (float(*)[33])smem;
    int tx = t & 31, ty = t >> 5;   // 32 x 8
    for (int r = ty; r < 32; r += 8) tile[r][tx] = bdn[(size_t)(by + r) * DD + bx + tx];
    __syncthreads();
    for (int r = ty; r < 32; r += 8)
      bdTb[(size_t)(bx + r) * DD + by + tx] = f2bf(tile[tx][r]);
  } else {
    size_t i = (size_t)(bid - 9232) * 256 + t;
    const float4* bf = (const float4*)bu;
    float4 v0 = bf[i * 2], v1 = bf[i * 2 + 1];
    short8 o;
    o[0] = (short)f2bf(v0.x); o[1] = (short)f2bf(v0.y);
    o[2] = (short)f2bf(v0.z); o[3] = (short)f2bf(v0.w);
    o[4] = (short)f2bf(v1.x); o[5] = (short)f2bf(v1.y);
    o[6] = (short)f2bf(v1.z); o[7] = (short)f2bf(v1.w);
    *(short8*)(bub + i * 8) = o;
  }
}

// ------- h partials: split-K over W1 (32 splits of 32) -------
__launch_bounds__(256)
__global__ void h_part_kernel(const float* __restrict__ c, const float* __restrict__ W1,
                              float* __restrict__ hpart) {
  int s = blockIdx.y;
  int j = blockIdx.x * 256 + threadIdx.x;
  int k0 = s * 32;
  __shared__ float cs[NB][32];
  for (int i = threadIdx.x; i < NB * 32; i += 256)
    cs[i >> 5][i & 31] = c[(size_t)(i >> 5) * DD + k0 + (i & 31)];
  __syncthreads();
  float acc[NB];
  #pragma unroll
  for (int b = 0; b < NB; b++) acc[b] = 0.f;
  #pragma unroll
  for (int al = 0; al < 32; al++) {
    float wv = W1[(size_t)(k0 + al) * DD + j];
    #pragma unroll
    for (int b = 0; b < NB; b++) acc[b] += cs[b][al] * wv;
  }
  #pragma unroll
  for (int b = 0; b < NB; b++)
    hpart[((size_t)s * NB + b) * DD + j] = acc[b];
}

// ------- h = gelu(sum_s hpart[s] + bias1) -------
__launch_bounds__(256)
__global__ void h_reduce_kernel(const float* __restrict__ hpart, const float* __restrict__ bias1,
                                float* __restrict__ h) {
  int idx = blockIdx.x * 256 + threadIdx.x;
  int j = idx & (DD - 1);
  float acc = bias1[j];
  #pragma unroll
  for (int s = 0; s < HSPLIT; s++) acc += hpart[(size_t)s * NB * DD + idx];
  h[idx] = gelu_f(acc);
}

// ------- w partials: LDS-staged W2 stream, split-K 16 x 64 rows -------
// grid (32 j-strips of 1024 f32, 16 k-splits) = 512 blocks = 2/CU.
#define WSTAGE(I8, BUF) do { int kr_ = k0 + (I8) * 8;                                \
    _Pragma("unroll")                                                                \
    for (int r_ = 0; r_ < 8; r_++)                                                   \
      gload_lds16f(W2 + (size_t)(kr_ + r_) * 32768 + j0 + t4, &wlds[BUF][r_][t4]);   \
  } while (0)

__launch_bounds__(256)
__global__ void w_part_kernel(const float* __restrict__ h, const float* __restrict__ W2,
                              float* __restrict__ part) {
  int s = blockIdx.y;
  int j0 = blockIdx.x * 1024;       // f32 column base
  int k0 = s * 64;
  int t = threadIdx.x;
  int t4 = t * 4;
  __shared__ __align__(16) float wlds[2][8][1024];   // 64 KB, double-buffered W2 tiles
  __shared__ __align__(16) float hlT[64][16];        // 4 KB, h slice [kk][b]

  // load h slice (transposed) into LDS
  float hv[4];
  #pragma unroll
  for (int v = 0; v < 4; v++) {
    int i = t + v * 256;            // (kk, b)
    hv[v] = h[(size_t)(i & 15) * DD + k0 + (i >> 4)];
  }
  #pragma unroll
  for (int v = 0; v < 4; v++) {
    int i = t + v * 256;
    hlT[i >> 4][i & 15] = hv[v];
  }

  WSTAGE(0, 0);
  WSTAGE(1, 1);

  f32x4 acc[NB];
  #pragma unroll
  for (int b = 0; b < NB; b++) acc[b] = f32x4{0.f, 0.f, 0.f, 0.f};

  #pragma unroll 1
  for (int i8 = 0; i8 < 8; i8++) {
    if (i8 < 7) { VMCNT8; } else { VMCNT0; }   // tile i8 resident (outstanding = i8+1's 8)
    BARRIER;                                   // all waves' staging + hlT writes visible
    int buf = i8 & 1;
    #pragma unroll
    for (int r = 0; r < 8; r++) {
      f32x4 wv = *(const f32x4*)&wlds[buf][r][t4];
      int kk = i8 * 8 + r;
      f32x4 hx0 = *(const f32x4*)&hlT[kk][0];
      f32x4 hx1 = *(const f32x4*)&hlT[kk][4];
      f32x4 hx2 = *(const f32x4*)&hlT[kk][8];
      f32x4 hx3 = *(const f32x4*)&hlT[kk][12];
      #pragma unroll
      for (int q = 0; q < 4; q++) {
        acc[q][0] += hx0[q] * wv[0]; acc[q][1] += hx0[q] * wv[1];
        acc[q][2] += hx0[q] * wv[2]; acc[q][3] += hx0[q] * wv[3];
        acc[q + 4][0] += hx1[q] * wv[0]; acc[q + 4][1] += hx1[q] * wv[1];
        acc[q + 4][2] += hx1[q] * wv[2]; acc[q + 4][3] += hx1[q] * wv[3];
        acc[q + 8][0] += hx2[q] * wv[0]; acc[q + 8][1] += hx2[q] * wv[1];
        acc[q + 8][2] += hx2[q] * wv[2]; acc[q + 8][3] += hx2[q] * wv[3];
        acc[q + 12][0] += hx3[q] * wv[0]; acc[q + 12][1] += hx3[q] * wv[1];
        acc[q + 12][2] += hx3[q] * wv[2]; acc[q + 12][3] += hx3[q] * wv[3];
      }
    }
    BARRIER;                                   // all waves done reading buf -> safe to overwrite
    if (i8 + 2 < 8) WSTAGE(i8 + 2, buf);
  }

  int j4 = blockIdx.x * 256 + t;               // float4 column index
  f32x4* pv = (f32x4*)part;
  #pragma unroll
  for (int b = 0; b < NB; b++)
    pv[((size_t)s * NB + b) * 8192 + j4] = acc[b];
}

// ------- w = sum_s part[s] + bias2 -------
__launch_bounds__(256)
__global__ void w_reduce_kernel(const float* __restrict__ part, const float* __restrict__ bias2,
                                float* __restrict__ w) {
  int idx = blockIdx.x * 256 + threadIdx.x;
  int j = idx & 32767;
  float acc = bias2[j];
  #pragma unroll
  for (int s = 0; s < WSPLIT; s++) acc += part[(size_t)s * NB * 32768 + idx];
  w[idx] = acc;
}

// ---- pack_lora: aext = zero-pad8(src @ colfactor), bext = zero-pad8(rowfactor) ----
__launch_bounds__(256)
__global__ void pack_lora_kernel(const u16* __restrict__ src, const float* __restrict__ w,
                                 int aoff, int boff,
                                 u16* __restrict__ aext, u16* __restrict__ bext) {
  int b = blockIdx.y;
  const float* wb = w + (size_t)b * 32768;
  int t = threadIdx.x;
  short8 z = {};
  if (blockIdx.x < 16) {
    __shared__ float a2s[8192];   // 32 KB col factor [d][r]
    for (int i = t; i < 8192; i += 256) a2s[i] = wb[aoff + i];
    __syncthreads();
    int row = blockIdx.x * 64 + (t >> 2);
    int q = t & 3;
    const u16* xr = src + ((size_t)b << 20) + (size_t)row * DD + q * 256;
    float acc[8] = {};
    #pragma unroll 4
    for (int kk = 0; kk < 32; kk++) {
      short8 xv = *(const short8*)(xr + kk * 8);
      #pragma unroll
      for (int e = 0; e < 8; e++) {
        float xf = bf2f((u16)xv[e]);
        int d = q * 256 + kk * 8 + e;
        #pragma unroll
        for (int r = 0; r < 8; r++) acc[r] += xf * a2s[d * 8 + r];
      }
    }
    #pragma unroll
    for (int r = 0; r < 8; r++) {
      acc[r] += __shfl_xor(acc[r], 1);
      acc[r] += __shfl_xor(acc[r], 2);
    }
    short8 ov = z;
    if (q == 0) {
      #pragma unroll
      for (int r = 0; r < 8; r++) ov[r] = (short)f2bf(acc[r]);
    }
    u16* orow = aext + ((size_t)b * 1024 + row) * 64 + q * 16;
    *(short8*)orow = ov;
    *(short8*)(orow + 8) = z;
  } else {
    for (int l = t; l < 1024; l += 256) {
      short8 ov;
      #pragma unroll
      for (int r = 0; r < 8; r++) ov[r] = (short)f2bf(wb[boff + l * 8 + r]);
      u16* orow = bext + ((size_t)b * 1024 + l) * 64;
      *(short8*)orow = ov;
      #pragma unroll
      for (int k = 1; k < 8; k++) *(short8*)(orow + k * 8) = z;
    }
  }
}

// ------- batched GEMM 256x256 tile, 8 waves, 4-phase, 32x32x16 MFMA, K=1024+64 -------
#define STAGE_A(KT, BUF) do { int kt_ = (KT);                                          \
    if (kt_ < 16) { int ks_ = kt_ * 64;                                                \
      _Pragma("unroll")                                                                \
      for (int c_ = 0; c_ < 4; c_++)                                                   \
        gload_lds16(Ab + (size_t)srow[c_] * DD + ks_ + se[c_], As[BUF] + ldsel[c_]);   \
    } else {                                                                           \
      _Pragma("unroll")                                                                \
      for (int c_ = 0; c_ < 4; c_++)                                                   \
        gload_lds16(Ae + (size_t)srow[c_] * 64 + se[c_], As[BUF] + ldsel[c_]);         \
    } } while (0)
#define STAGE_B(KT, BUF) do { int kt_ = (KT);                                          \
    if (kt_ < 16) { int ks_ = kt_ * 64;                                                \
      _Pragma("unroll")                                                                \
      for (int c_ = 0; c_ < 4; c_++)                                                   \
        gload_lds16(Bb + (size_t)srow[c_] * DD + ks_ + se[c_], Bs[BUF] + ldsel[c_]);   \
    } else {                                                                           \
      _Pragma("unroll")                                                                \
      for (int c_ = 0; c_ < 4; c_++)                                                   \
        gload_lds16(Be + (size_t)srow[c_] * 64 + se[c_], Bs[BUF] + ldsel[c_]);         \
    } } while (0)

template<int PHASE>
__launch_bounds__(512, 2)
__global__ void gemm256_kernel(const u16* __restrict__ A, const u16* __restrict__ BT,
                               const u16* __restrict__ Aext, const u16* __restrict__ Bext,
                               const u16* __restrict__ resid, void* __restrict__ Cout) {
  constexpr int BK = 64;
  constexpr int NT = 17;
  __shared__ __align__(16) u16 As[2][256 * BK];
  __shared__ __align__(16) u16 Bs[2][256 * BK];

  int orig = blockIdx.x;
  int logical = (orig & 7) * 32 + (orig >> 3);
  int b = logical >> 4;
  int tile = logical & 15;
  int tm = tile >> 2, tn = tile & 3;

  const u16* Ab = A + ((size_t)b << 20) + (size_t)(tm * 256) * DD;
  const u16* Bb = BT + (size_t)(tn * 256) * DD;                       // batch-shared
  const u16* Ae = Aext + ((size_t)b * 1024 + tm * 256) * 64;
  const u16* Be = Bext + ((size_t)b * 1024 + tn * 256) * 64;

  int t = threadIdx.x, lane = t & 63;
  int l31 = lane & 31, kb = (lane >> 5) * 8;   // k-octet select for 32x32 frags
  int wave = t >> 6;
  int wm = wave >> 2, wn = wave & 3;           // per-wave 128 x 64 output

  int srow[4], se[4], ldsel[4];
  #pragma unroll
  for (int c = 0; c < 4; c++) {
    int chunk = c * 512 + t;
    srow[c] = chunk >> 3;
    se[c] = ((chunk & 7) ^ (srow[c] & 7)) << 3;
    ldsel[c] = chunk * 8;
  }

  f32x16 acc[4][2] = {};    // 4 row-tiles(32) x 2 col-tiles(32)

  STAGE_A(0, 0); STAGE_B(0, 0);
  STAGE_A(1, 1); STAGE_B(1, 1);
  VMCNT8;
  BARRIER;

  int cur = 0;
  #pragma unroll 1
  for (int kt = 0; kt < NT; kt++) {
    const u16* Ap = As[cur];
    const u16* Bp = Bs[cur];
    short8 afr[2][4], bf0[4], bf1[4];   // [rt][ks] / [ks]

    // ---- ph0: read A rt{0,1} (8) + B ct0 (4); Q00 ----
    #pragma unroll
    for (int ks = 0; ks < 4; ks++) {
      #pragma unroll
      for (int rt = 0; rt < 2; rt++) {
        int r = wm * 128 + rt * 32 + l31;
        int e = (ks * 16 + kb) ^ ((r & 7) << 3);
        afr[rt][ks] = *(const short8*)(Ap + r * BK + e);
      }
      {
        int r = wn * 64 + l31;
        int e = (ks * 16 + kb) ^ ((r & 7) << 3);
        bf0[ks] = *(const short8*)(Bp + r * BK + e);
      }
    }
    BARRIER;
    __builtin_amdgcn_s_setprio(1);
    #pragma unroll
    for (int ks = 0; ks < 4; ks++)
      #pragma unroll
      for (int rt = 0; rt < 2; rt++)
        acc[rt][0] = __builtin_amdgcn_mfma_f32_32x32x16_bf16(afr[rt][ks], bf0[ks], acc[rt][0], 0, 0, 0);
    __builtin_amdgcn_s_setprio(0);
    BARRIER;

    // ---- ph1: read B ct1 (4); Q01 ----
    #pragma unroll
    for (int ks = 0; ks < 4; ks++) {
      int r = wn * 64 + 32 + l31;
      int e = (ks * 16 + kb) ^ ((r & 7) << 3);
      bf1[ks] = *(const short8*)(Bp + r * BK + e);
    }
    BARRIER;
    __builtin_amdgcn_s_setprio(1);
    #pragma unroll
    for (int ks = 0; ks < 4; ks++)
      #pragma unroll
      for (int rt = 0; rt < 2; rt++)
        acc[rt][1] = __builtin_amdgcn_mfma_f32_32x32x16_bf16(afr[rt][ks], bf1[ks], acc[rt][1], 0, 0, 0);
    __builtin_amdgcn_s_setprio(0);
    BARRIER;
    // all B reads of buf[cur] done -> B slot free

    // ---- ph2: stage B(kt+2); read A rt{2,3} (8); Q11 ----
    if (kt + 2 < NT) STAGE_B(kt + 2, cur);
    #pragma unroll
    for (int ks = 0; ks < 4; ks++)
      #pragma unroll
      for (int rt = 0; rt < 2; rt++) {
        int r = wm * 128 + (rt + 2) * 32 + l31;
        int e = (ks * 16 + kb) ^ ((r & 7) << 3);
        afr[rt][ks] = *(const short8*)(Ap + r * BK + e);
      }
    BARRIER;
    __builtin_amdgcn_s_setprio(1);
    #pragma unroll
    for (int ks = 0; ks < 4; ks++)
      #pragma unroll
      for (int rt = 0; rt < 2; rt++)
        acc[rt + 2][1] = __builtin_amdgcn_mfma_f32_32x32x16_bf16(afr[rt][ks], bf1[ks], acc[rt + 2][1], 0, 0, 0);
    __builtin_amdgcn_s_setprio(0);
    BARRIER;
    // all A reads of buf[cur] done -> A slot free

    // ---- ph3: stage A(kt+2); Q10 (regs only); tile-boundary wait ----
    if (kt + 2 < NT) STAGE_A(kt + 2, cur);
    __builtin_amdgcn_s_setprio(1);
    #pragma unroll
    for (int ks = 0; ks < 4; ks++)
      #pragma unroll
      for (int rt = 0; rt < 2; rt++)
        acc[rt + 2][0] = __builtin_amdgcn_mfma_f32_32x32x16_bf16(afr[rt][ks], bf0[ks], acc[rt + 2][0], 0, 0, 0);
    __builtin_amdgcn_s_setprio(0);
    if (kt + 2 < NT) { VMCNT8; } else { VMCNT0; }
    BARRIER;

    cur ^= 1;
  }

  // C/D map (verified m74/m101): col = l31, row = (reg&3) + 8*(reg>>2) + 4*(lane>>5)
  int r0 = tm * 256 + wm * 128 + (lane >> 5) * 4;
  int c0 = tn * 256 + wn * 64 + l31;
  if (PHASE == 1) {
    u16* mid = (u16*)Cout + ((size_t)b << 20);
    #pragma unroll
    for (int rt = 0; rt < 4; rt++)
      #pragma unroll
      for (int ct = 0; ct < 2; ct++)
        #pragma unroll
        for (int reg = 0; reg < 16; reg++) {
          int row = r0 + rt * 32 + (reg & 3) + 8 * (reg >> 2);
          int col = c0 + ct * 32;
          mid[(size_t)row * DD + col] = f2bf(gelu_f(acc[rt][ct][reg]));
        }
  } else {
    float* out = (float*)Cout + ((size_t)b << 20);
    const u16* xb = resid + ((size_t)b << 20);
    #pragma unroll
    for (int rt = 0; rt < 4; rt++)
      #pragma unroll
      for (int ct = 0; ct < 2; ct++)
        #pragma unroll
        for (int reg = 0; reg < 16; reg++) {
          int row = r0 + rt * 32 + (reg & 3) + 8 * (reg >> 2);
          int col = c0 + ct * 32;
          size_t idx = (size_t)row * DD + col;
          out[idx] = bf2f(xb[idx]) + acc[rt][ct][reg];
        }
  }
}

extern "C" void kernel_launch(void* const* d_in, const int* in_sizes, int n_in,
                              void* d_out, int out_size, void* d_ws, size_t ws_size,
                              hipStream_t stream) {
  const float* x         = (const float*)d_in[0];
  const float* ada       = (const float*)d_in[1];
  const float* base_up   = (const float*)d_in[2];
  const float* base_down = (const float*)d_in[3];
  const float* gamma     = (const float*)d_in[4];
  const float* beta      = (const float*)d_in[5];
  const float* W1        = (const float*)d_in[6];
  const float* bias1     = (const float*)d_in[7];
  const float* W2        = (const float*)d_in[8];
  const float* bias2     = (const float*)d_in[9];
  float* out = (float*)d_out;
  char* ws = (char*)d_ws;

  float* c     = (float*)(ws);                 // 64 KB
  float* h     = (float*)(ws + 0x10000);       // 64 KB
  float* w     = (float*)(ws + 0x20000);       // 2 MB
  u16*   bdTb  = (u16*)  (ws + 0x220000);      // 2 MB
  u16*   bub   = (u16*)  (ws + 0x420000);      // 2 MB
  float* hpart = (float*)(ws + 0x620000);      // 2 MB
  u16*   xb    = (u16*)  (ws + 0x820000);      // 32 MB
  u16*   uext  = (u16*)  (ws + 0x2820000);     // 2 MB
  u16*   b2ext = (u16*)  (ws + 0x2A20000);     // 2 MB
  u16*   vext  = (u16*)  (ws + 0x2C20000);     // 2 MB
  u16*   a1ext = (u16*)  (ws + 0x2E20000);     // 2 MB
  u16*   mid   = (u16*)  (ws + 0x3020000);     // 32 MB
  float* part  = (float*)(ws + 0x5020000);     // 32 MB

  prep_kernel<<<dim3(9744), dim3(256), 0, stream>>>(x, xb, ada, gamma, beta, c,
                                                    base_down, bdTb, base_up, bub);
  h_part_kernel<<<dim3(4, HSPLIT), dim3(256), 0, stream>>>(c, W1, hpart);
  h_reduce_kernel<<<dim3(64), dim3(256), 0, stream>>>(hpart, bias1, h);
  w_part_kernel<<<dim3(32, WSPLIT), dim3(256), 0, stream>>>(h, W2, part);
  w_reduce_kernel<<<dim3(2048), dim3(256), 0, stream>>>(part, bias2, w);
  pack_lora_kernel<<<dim3(17, 16), dim3(256), 0, stream>>>(xb, w, 16384, 24576, uext, b2ext);
  gemm256_kernel<1><<<dim3(256), dim3(512), 0, stream>>>(xb, bdTb, uext, b2ext,
                                                         (const u16*)nullptr, (void*)mid);
  pack_lora_kernel<<<dim3(17, 16), dim3(256), 0, stream>>>(mid, w, 8192, 0, vext, a1ext);
  gemm256_kernel<2><<<dim3(256), dim3(512), 0, stream>>>(mid, bub, vext, a1ext, xb, (void*)out);
}

// Round 10
// 254.609 us; speedup vs baseline: 1.1157x; 1.0138x over previous
//
#include <hip/hip_runtime.h>
#include <math.h>

#define DD 1024
#define NB 16
#define WSPLIT 4
#define HSPLIT 32

typedef unsigned short u16;
typedef __attribute__((ext_vector_type(8))) short short8;
typedef __attribute__((ext_vector_type(4))) float f32x4;
typedef __attribute__((ext_vector_type(16))) float f32x16;

__device__ __forceinline__ float gelu_f(float x) {
  return 0.5f * x * (1.0f + erff(x * 0.70710678118654752440f));
}
__device__ __forceinline__ u16 f2bf(float f) {
  union { float f; unsigned u; } v; v.f = f;
  return (u16)((v.u + 0x7FFFu + ((v.u >> 16) & 1u)) >> 16);
}
__device__ __forceinline__ float bf2f(u16 b) {
  union { unsigned u; float f; } v; v.u = ((unsigned)b) << 16;
  return v.f;
}
__device__ __forceinline__ void gload_lds16(const u16* g, u16* l) {
  __builtin_amdgcn_global_load_lds(
      (const __attribute__((address_space(1))) void*)g,
      (__attribute__((address_space(3))) void*)l, 16, 0, 0);
}
__device__ __forceinline__ void gload_lds16f(const float* g, float* l) {
  __builtin_amdgcn_global_load_lds(
      (const __attribute__((address_space(1))) void*)g,
      (__attribute__((address_space(3))) void*)l, 16, 0, 0);
}

#define VMCNT8   asm volatile("s_waitcnt vmcnt(8)" ::: "memory")
#define VMCNT4   asm volatile("s_waitcnt vmcnt(4)" ::: "memory")
#define VMCNT0   asm volatile("s_waitcnt vmcnt(0)" ::: "memory")
#define BARRIER  asm volatile("s_barrier" ::: "memory")

// ---- fused prep: cvt x | LN | transpose+cvt base_down | cvt base_up ----
__launch_bounds__(256)
__global__ void prep_kernel(const float* __restrict__ x, u16* __restrict__ xb,
                            const float* __restrict__ ada, const float* __restrict__ gamma,
                            const float* __restrict__ beta, float* __restrict__ c,
                            const float* __restrict__ bdn, u16* __restrict__ bdTb,
                            const float* __restrict__ bu, u16* __restrict__ bub) {
  __shared__ float smem[1056];
  int bid = blockIdx.x;
  int t = threadIdx.x;
  if (bid < 8192) {
    size_t i = (size_t)bid * 256 + t;
    const float4* xf = (const float4*)x;
    float4 v0 = xf[i * 2], v1 = xf[i * 2 + 1];
    short8 o;
    o[0] = (short)f2bf(v0.x); o[1] = (short)f2bf(v0.y);
    o[2] = (short)f2bf(v0.z); o[3] = (short)f2bf(v0.w);
    o[4] = (short)f2bf(v1.x); o[5] = (short)f2bf(v1.y);
    o[6] = (short)f2bf(v1.z); o[7] = (short)f2bf(v1.w);
    *(short8*)(xb + i * 8) = o;
  } else if (bid < 8208) {
    int b = bid - 8192;
    const float* row = ada + b * DD;
    float s = 0.f, s2 = 0.f;
    for (int i = t; i < DD; i += 256) { float v = row[i]; s += v; s2 += v * v; }
    for (int off = 32; off; off >>= 1) { s += __shfl_down(s, off); s2 += __shfl_down(s2, off); }
    float* rs = smem; float* rs2 = smem + 4;
    int wave = t >> 6, lane = t & 63;
    if (lane == 0) { rs[wave] = s; rs2[wave] = s2; }
    __syncthreads();
    if (t == 0) {
      float a = 0.f, a2 = 0.f;
      for (int w = 0; w < 4; w++) { a += rs[w]; a2 += rs2[w]; }
      rs[0] = a * (1.0f / DD); rs2[0] = a2 * (1.0f / DD);
    }
    __syncthreads();
    float mu = rs[0];
    float var = rs2[0] - mu * mu;
    float inv = rsqrtf(var + 1e-5f);
    for (int i = t; i < DD; i += 256)
      c[b * DD + i] = (row[i] - mu) * inv * gamma[i] + beta[i];
  } else if (bid < 9232) {
    int t2 = bid - 8208;
    int bx = (t2 & 31) * 32, by = (t2 >> 5) * 32;
    float (*tile)[33] = (float(*)[33])smem;
    int tx = t & 31, ty = t >> 5;   // 32 x 8
    for (int r = ty; r < 32; r += 8) tile[r][tx] = bdn[(size_t)(by + r) * DD + bx + tx];
    __syncthreads();
    for (int r = ty; r < 32; r += 8)
      bdTb[(size_t)(bx + r) * DD + by + tx] = f2bf(tile[tx][r]);
  } else {
    size_t i = (size_t)(bid - 9232) * 256 + t;
    const float4* bf = (const float4*)bu;
    float4 v0 = bf[i * 2], v1 = bf[i * 2 + 1];
    short8 o;
    o[0] = (short)f2bf(v0.x); o[1] = (short)f2bf(v0.y);
    o[2] = (short)f2bf(v0.z); o[3] = (short)f2bf(v0.w);
    o[4] = (short)f2bf(v1.x); o[5] = (short)f2bf(v1.y);
    o[6] = (short)f2bf(v1.z); o[7] = (short)f2bf(v1.w);
    *(short8*)(bub + i * 8) = o;
  }
}

// ------- h partials: split-K over W1 (32 splits of 32) -------
__launch_bounds__(256)
__global__ void h_part_kernel(const float* __restrict__ c, const float* __restrict__ W1,
                              float* __restrict__ hpart) {
  int s = blockIdx.y;
  int j = blockIdx.x * 256 + threadIdx.x;
  int k0 = s * 32;
  __shared__ float cs[NB][32];
  for (int i = threadIdx.x; i < NB * 32; i += 256)
    cs[i >> 5][i & 31] = c[(size_t)(i >> 5) * DD + k0 + (i & 31)];
  __syncthreads();
  float acc[NB];
  #pragma unroll
  for (int b = 0; b < NB; b++) acc[b] = 0.f;
  #pragma unroll
  for (int al = 0; al < 32; al++) {
    float wv = W1[(size_t)(k0 + al) * DD + j];
    #pragma unroll
    for (int b = 0; b < NB; b++) acc[b] += cs[b][al] * wv;
  }
  #pragma unroll
  for (int b = 0; b < NB; b++)
    hpart[((size_t)s * NB + b) * DD + j] = acc[b];
}

// ------- h = gelu(sum_s hpart[s] + bias1) -------
__launch_bounds__(256)
__global__ void h_reduce_kernel(const float* __restrict__ hpart, const float* __restrict__ bias1,
                                float* __restrict__ h) {
  int idx = blockIdx.x * 256 + threadIdx.x;
  int j = idx & (DD - 1);
  float acc = bias1[j];
  #pragma unroll
  for (int s = 0; s < HSPLIT; s++) acc += hpart[(size_t)s * NB * DD + idx];
  h[idx] = gelu_f(acc);
}

// ------- w partials: LDS-staged W2 stream; 4 k-splits x 128 j-strips of 256 cols -------
#define WSTAGE(ST, BUF) do { int kr_ = k0 + (ST) * 16;                                      \
    _Pragma("unroll")                                                                       \
    for (int i_ = 0; i_ < 4; i_++)                                                          \
      gload_lds16f(W2 + (size_t)(kr_ + i_ * 4 + (t >> 6)) * 32768 + j0 + ((t & 63) << 2),   \
                   &wlds[BUF][i_ * 4 + (t >> 6)][(t & 63) << 2]);                           \
  } while (0)

__launch_bounds__(256)
__global__ void w_part_kernel(const float* __restrict__ h, const float* __restrict__ W2,
                              float* __restrict__ part) {
  int s = blockIdx.y;               // 0..3
  int j0 = blockIdx.x * 256;        // f32 col base, grid.x = 128
  int k0 = s * 256;
  int t = threadIdx.x;
  __shared__ __align__(16) float wlds[2][16][256];   // 32 KB, double-buffered W2 tiles
  __shared__ __align__(16) float hlT[256][20];       // 20 KB, h slice transposed (pad 20)

  // h slice -> LDS transposed: hlT[kk][b]
  #pragma unroll
  for (int v = 0; v < 16; v++) {
    int i = t + v * 256;            // (b = i>>8, kk = i&255), coalesced global read
    hlT[i & 255][i >> 8] = h[(size_t)(i >> 8) * DD + k0 + (i & 255)];
  }

  WSTAGE(0, 0);
  WSTAGE(1, 1);

  float acc[NB] = {};

  #pragma unroll 1
  for (int st = 0; st < 16; st++) {
    if (st < 15) { VMCNT4; } else { VMCNT0; }   // tile st resident
    BARRIER;                                    // staging + hlT visible to all waves
    int buf = st & 1;
    #pragma unroll
    for (int r = 0; r < 16; r++) {
      float wv = wlds[buf][r][t];
      int kk = st * 16 + r;
      f32x4 h0 = *(const f32x4*)&hlT[kk][0];
      f32x4 h1 = *(const f32x4*)&hlT[kk][4];
      f32x4 h2 = *(const f32x4*)&hlT[kk][8];
      f32x4 h3 = *(const f32x4*)&hlT[kk][12];
      #pragma unroll
      for (int q = 0; q < 4; q++) {
        acc[q]      += h0[q] * wv;
        acc[q + 4]  += h1[q] * wv;
        acc[q + 8]  += h2[q] * wv;
        acc[q + 12] += h3[q] * wv;
      }
    }
    BARRIER;                                    // all waves done with buf -> overwrite ok
    if (st + 2 < 16) WSTAGE(st + 2, buf);
  }

  #pragma unroll
  for (int b = 0; b < NB; b++)
    part[((size_t)s * NB + b) * 32768 + j0 + t] = acc[b];
}

// ------- w = sum_s part[s] + bias2 -------
__launch_bounds__(256)
__global__ void w_reduce_kernel(const float* __restrict__ part, const float* __restrict__ bias2,
                                float* __restrict__ w) {
  int idx = blockIdx.x * 256 + threadIdx.x;
  int j = idx & 32767;
  float acc = bias2[j];
  #pragma unroll
  for (int s = 0; s < WSPLIT; s++) acc += part[(size_t)s * NB * 32768 + idx];
  w[idx] = acc;
}

// ---- pack_lora: aext = zero-pad8(src @ colfactor), bext = zero-pad8(rowfactor) ----
__launch_bounds__(256)
__global__ void pack_lora_kernel(const u16* __restrict__ src, const float* __restrict__ w,
                                 int aoff, int boff,
                                 u16* __restrict__ aext, u16* __restrict__ bext) {
  int b = blockIdx.y;
  const float* wb = w + (size_t)b * 32768;
  int t = threadIdx.x;
  short8 z = {};
  if (blockIdx.x < 16) {
    __shared__ float a2s[8192];   // 32 KB col factor [d][r]
    for (int i = t; i < 8192; i += 256) a2s[i] = wb[aoff + i];
    __syncthreads();
    int row = blockIdx.x * 64 + (t >> 2);
    int q = t & 3;
    const u16* xr = src + ((size_t)b << 20) + (size_t)row * DD + q * 256;
    float acc[8] = {};
    #pragma unroll 4
    for (int kk = 0; kk < 32; kk++) {
      short8 xv = *(const short8*)(xr + kk * 8);
      #pragma unroll
      for (int e = 0; e < 8; e++) {
        float xf = bf2f((u16)xv[e]);
        int d = q * 256 + kk * 8 + e;
        #pragma unroll
        for (int r = 0; r < 8; r++) acc[r] += xf * a2s[d * 8 + r];
      }
    }
    #pragma unroll
    for (int r = 0; r < 8; r++) {
      acc[r] += __shfl_xor(acc[r], 1);
      acc[r] += __shfl_xor(acc[r], 2);
    }
    short8 ov = z;
    if (q == 0) {
      #pragma unroll
      for (int r = 0; r < 8; r++) ov[r] = (short)f2bf(acc[r]);
    }
    u16* orow = aext + ((size_t)b * 1024 + row) * 64 + q * 16;
    *(short8*)orow = ov;
    *(short8*)(orow + 8) = z;
  } else {
    for (int l = t; l < 1024; l += 256) {
      short8 ov;
      #pragma unroll
      for (int r = 0; r < 8; r++) ov[r] = (short)f2bf(wb[boff + l * 8 + r]);
      u16* orow = bext + ((size_t)b * 1024 + l) * 64;
      *(short8*)orow = ov;
      #pragma unroll
      for (int k = 1; k < 8; k++) *(short8*)(orow + k * 8) = z;
    }
  }
}

// ------- batched GEMM 256x256 tile, 8 waves, 2-barrier/K-tile + counted vmcnt -------
// 32x32x16 MFMA, K = 1024 + 64(rank-8 ext).  Reads+MFMA form one flat region per
// K-tile (compiler interleaves via fine lgkmcnt); barriers only around staging.
#define STAGE_A(KT, BUF) do { int kt_ = (KT);                                          \
    if (kt_ < 16) { int ks_ = kt_ * 64;                                                \
      _Pragma("unroll")                                                                \
      for (int c_ = 0; c_ < 4; c_++)                                                   \
        gload_lds16(Ab + (size_t)srow[c_] * DD + ks_ + se[c_], As[BUF] + ldsel[c_]);   \
    } else {                                                                           \
      _Pragma("unroll")                                                                \
      for (int c_ = 0; c_ < 4; c_++)                                                   \
        gload_lds16(Ae + (size_t)srow[c_] * 64 + se[c_], As[BUF] + ldsel[c_]);         \
    } } while (0)
#define STAGE_B(KT, BUF) do { int kt_ = (KT);                                          \
    if (kt_ < 16) { int ks_ = kt_ * 64;                                                \
      _Pragma("unroll")                                                                \
      for (int c_ = 0; c_ < 4; c_++)                                                   \
        gload_lds16(Bb + (size_t)srow[c_] * DD + ks_ + se[c_], Bs[BUF] + ldsel[c_]);   \
    } else {                                                                           \
      _Pragma("unroll")                                                                \
      for (int c_ = 0; c_ < 4; c_++)                                                   \
        gload_lds16(Be + (size_t)srow[c_] * 64 + se[c_], Bs[BUF] + ldsel[c_]);         \
    } } while (0)

template<int PHASE>
__launch_bounds__(512, 2)
__global__ void gemm256_kernel(const u16* __restrict__ A, const u16* __restrict__ BT,
                               const u16* __restrict__ Aext, const u16* __restrict__ Bext,
                               const u16* __restrict__ resid, void* __restrict__ Cout) {
  constexpr int BK = 64;
  constexpr int NT = 17;
  __shared__ __align__(16) u16 As[2][256 * BK];
  __shared__ __align__(16) u16 Bs[2][256 * BK];

  int orig = blockIdx.x;
  int logical = (orig & 7) * 32 + (orig >> 3);
  int b = logical >> 4;
  int tile = logical & 15;
  int tm = tile >> 2, tn = tile & 3;

  const u16* Ab = A + ((size_t)b << 20) + (size_t)(tm * 256) * DD;
  const u16* Bb = BT + (size_t)(tn * 256) * DD;                       // batch-shared
  const u16* Ae = Aext + ((size_t)b * 1024 + tm * 256) * 64;
  const u16* Be = Bext + ((size_t)b * 1024 + tn * 256) * 64;

  int t = threadIdx.x, lane = t & 63;
  int l31 = lane & 31, kb = (lane >> 5) * 8;   // k-octet select for 32x32 frags
  int wave = t >> 6;
  int wm = wave >> 2, wn = wave & 3;           // per-wave 128 x 64 output

  int srow[4], se[4], ldsel[4];
  #pragma unroll
  for (int c = 0; c < 4; c++) {
    int chunk = c * 512 + t;
    srow[c] = chunk >> 3;
    se[c] = ((chunk & 7) ^ (srow[c] & 7)) << 3;
    ldsel[c] = chunk * 8;
  }

  f32x16 acc[4][2] = {};    // 4 row-tiles(32) x 2 col-tiles(32)

  STAGE_A(0, 0); STAGE_B(0, 0);
  STAGE_A(1, 1); STAGE_B(1, 1);
  VMCNT8;
  BARRIER;

  int cur = 0;
  #pragma unroll 1
  for (int kt = 0; kt < NT; kt++) {
    const u16* Ap = As[cur];
    const u16* Bp = Bs[cur];
    short8 afr[2][4], bf0[4], bf1[4];

    // ---- flat region: reads + 4 MFMA clusters, no intra-tile barriers ----
    #pragma unroll
    for (int ks = 0; ks < 4; ks++) {
      #pragma unroll
      for (int rt = 0; rt < 2; rt++) {
        int r = wm * 128 + rt * 32 + l31;
        int e = (ks * 16 + kb) ^ ((r & 7) << 3);
        afr[rt][ks] = *(const short8*)(Ap + r * BK + e);
      }
      {
        int r = wn * 64 + l31;
        int e = (ks * 16 + kb) ^ ((r & 7) << 3);
        bf0[ks] = *(const short8*)(Bp + r * BK + e);
      }
    }
    __builtin_amdgcn_s_setprio(1);
    #pragma unroll
    for (int ks = 0; ks < 4; ks++)
      #pragma unroll
      for (int rt = 0; rt < 2; rt++)
        acc[rt][0] = __builtin_amdgcn_mfma_f32_32x32x16_bf16(afr[rt][ks], bf0[ks], acc[rt][0], 0, 0, 0);
    __builtin_amdgcn_s_setprio(0);

    #pragma unroll
    for (int ks = 0; ks < 4; ks++) {
      int r = wn * 64 + 32 + l31;
      int e = (ks * 16 + kb) ^ ((r & 7) << 3);
      bf1[ks] = *(const short8*)(Bp + r * BK + e);
    }
    __builtin_amdgcn_s_setprio(1);
    #pragma unroll
    for (int ks = 0; ks < 4; ks++)
      #pragma unroll
      for (int rt = 0; rt < 2; rt++)
        acc[rt][1] = __builtin_amdgcn_mfma_f32_32x32x16_bf16(afr[rt][ks], bf1[ks], acc[rt][1], 0, 0, 0);
    __builtin_amdgcn_s_setprio(0);

    #pragma unroll
    for (int ks = 0; ks < 4; ks++)
      #pragma unroll
      for (int rt = 0; rt < 2; rt++) {
        int r = wm * 128 + (rt + 2) * 32 + l31;
        int e = (ks * 16 + kb) ^ ((r & 7) << 3);
        afr[rt][ks] = *(const short8*)(Ap + r * BK + e);
      }
    __builtin_amdgcn_s_setprio(1);
    #pragma unroll
    for (int ks = 0; ks < 4; ks++)
      #pragma unroll
      for (int rt = 0; rt < 2; rt++)
        acc[rt + 2][1] = __builtin_amdgcn_mfma_f32_32x32x16_bf16(afr[rt][ks], bf1[ks], acc[rt + 2][1], 0, 0, 0);

    #pragma unroll
    for (int ks = 0; ks < 4; ks++)
      #pragma unroll
      for (int rt = 0; rt < 2; rt++)
        acc[rt + 2][0] = __builtin_amdgcn_mfma_f32_32x32x16_bf16(afr[rt][ks], bf0[ks], acc[rt + 2][0], 0, 0, 0);
    __builtin_amdgcn_s_setprio(0);

    BARRIER;   // all waves' reads of buf[cur] complete (every read consumed by MFMA above)
    if (kt + 2 < NT) {
      STAGE_B(kt + 2, cur);
      STAGE_A(kt + 2, cur);
      VMCNT8;  // oldest 8 (= kt+1's) retired -> buf[cur^1] resident for this wave
    } else {
      VMCNT0;
    }
    BARRIER;   // all waves' vmcnt passed -> buf[cur^1] fully populated

    cur ^= 1;
  }

  // C/D map (verified m74/m101): col = l31, row = (reg&3) + 8*(reg>>2) + 4*(lane>>5)
  int r0 = tm * 256 + wm * 128 + (lane >> 5) * 4;
  int c0 = tn * 256 + wn * 64 + l31;
  if (PHASE == 1) {
    u16* mid = (u16*)Cout + ((size_t)b << 20);
    #pragma unroll
    for (int rt = 0; rt < 4; rt++)
      #pragma unroll
      for (int ct = 0; ct < 2; ct++)
        #pragma unroll
        for (int reg = 0; reg < 16; reg++) {
          int row = r0 + rt * 32 + (reg & 3) + 8 * (reg >> 2);
          int col = c0 + ct * 32;
          mid[(size_t)row * DD + col] = f2bf(gelu_f(acc[rt][ct][reg]));
        }
  } else {
    float* out = (float*)Cout + ((size_t)b << 20);
    const u16* xb = resid + ((size_t)b << 20);
    #pragma unroll
    for (int rt = 0; rt < 4; rt++)
      #pragma unroll
      for (int ct = 0; ct < 2; ct++)
        #pragma unroll
        for (int reg = 0; reg < 16; reg++) {
          int row = r0 + rt * 32 + (reg & 3) + 8 * (reg >> 2);
          int col = c0 + ct * 32;
          size_t idx = (size_t)row * DD + col;
          out[idx] = bf2f(xb[idx]) + acc[rt][ct][reg];
        }
  }
}

extern "C" void kernel_launch(void* const* d_in, const int* in_sizes, int n_in,
                              void* d_out, int out_size, void* d_ws, size_t ws_size,
                              hipStream_t stream) {
  const float* x         = (const float*)d_in[0];
  const float* ada       = (const float*)d_in[1];
  const float* base_up   = (const float*)d_in[2];
  const float* base_down = (const float*)d_in[3];
  const float* gamma     = (const float*)d_in[4];
  const float* beta      = (const float*)d_in[5];
  const float* W1        = (const float*)d_in[6];
  const float* bias1     = (const float*)d_in[7];
  const float* W2        = (const float*)d_in[8];
  const float* bias2     = (const float*)d_in[9];
  float* out = (float*)d_out;
  char* ws = (char*)d_ws;

  float* c     = (float*)(ws);                 // 64 KB
  float* h     = (float*)(ws + 0x10000);       // 64 KB
  float* w     = (float*)(ws + 0x20000);       // 2 MB
  u16*   bdTb  = (u16*)  (ws + 0x220000);      // 2 MB
  u16*   bub   = (u16*)  (ws + 0x420000);      // 2 MB
  float* hpart = (float*)(ws + 0x620000);      // 2 MB
  u16*   xb    = (u16*)  (ws + 0x820000);      // 32 MB
  u16*   uext  = (u16*)  (ws + 0x2820000);     // 2 MB
  u16*   b2ext = (u16*)  (ws + 0x2A20000);     // 2 MB
  u16*   vext  = (u16*)  (ws + 0x2C20000);     // 2 MB
  u16*   a1ext = (u16*)  (ws + 0x2E20000);     // 2 MB
  u16*   mid   = (u16*)  (ws + 0x3020000);     // 32 MB
  float* part  = (float*)(ws + 0x5020000);     // 8 MB

  prep_kernel<<<dim3(9744), dim3(256), 0, stream>>>(x, xb, ada, gamma, beta, c,
                                                    base_down, bdTb, base_up, bub);
  h_part_kernel<<<dim3(4, HSPLIT), dim3(256), 0, stream>>>(c, W1, hpart);
  h_reduce_kernel<<<dim3(64), dim3(256), 0, stream>>>(hpart, bias1, h);
  w_part_kernel<<<dim3(128, WSPLIT), dim3(256), 0, stream>>>(h, W2, part);
  w_reduce_kernel<<<dim3(2048), dim3(256), 0, stream>>>(part, bias2, w);
  pack_lora_kernel<<<dim3(17, 16), dim3(256), 0, stream>>>(xb, w, 16384, 24576, uext, b2ext);
  gemm256_kernel<1><<<dim3(256), dim3(512), 0, stream>>>(xb, bdTb, uext, b2ext,
                                                         (const u16*)nullptr, (void*)mid);
  pack_lora_kernel<<<dim3(17, 16), dim3(256), 0, stream>>>(mid, w, 8192, 0, vext, a1ext);
  gemm256_kernel<2><<<dim3(256), dim3(512), 0, stream>>>(mid, bub, vext, a1ext, xb, (void*)out);
}